// Round 8
// baseline (391.591 us; speedup 1.0000x reference)
//
#include <hip/hip_runtime.h>
#include <hip/hip_bf16.h>

#define NN 100000
#define NE 1280000
#define DD 64
#define NRANGE 98            // ceil(NN/1024)
#define GPB 5                // groups per persistent block
#define FGRID 1250           // 1250 * 5 * 16 = 100000 nodes (exact)

typedef __attribute__((ext_vector_type(8))) short bf16x8;
typedef __attribute__((ext_vector_type(4))) float f32x4;

static __device__ __forceinline__ unsigned short f2bf(float f) {
    __hip_bfloat16 h = __float2bfloat16(f);
    return *reinterpret_cast<unsigned short*>(&h);
}

// ---------------------------------------------------------------------------
// x (fp32) -> bf16 copy. Grid 6250 x 256, 4 elems/thread (exact: 6.4M).
// ---------------------------------------------------------------------------
__global__ __launch_bounds__(256) void f32_to_bf16_kernel(
    const float* __restrict__ in, unsigned short* __restrict__ out)
{
    int i = (blockIdx.x * 256 + threadIdx.x) * 4;
    float4 v = *(const float4*)(in + i);
    ushort4 o;
    o.x = f2bf(v.x); o.y = f2bf(v.y); o.z = f2bf(v.z); o.w = f2bf(v.w);
    *(ushort4*)(out + i) = o;
}

// ---------------------------------------------------------------------------
// Range histogram: count edges per 1024-node dst range. LDS-staged.
// ---------------------------------------------------------------------------
__global__ __launch_bounds__(256) void hist2_kernel(
    const int* __restrict__ dst, int* __restrict__ rangeCnt)
{
    __shared__ int h[128];
    int tid = threadIdx.x;
    if (tid < 128) h[tid] = 0;
    __syncthreads();
    int e0 = blockIdx.x * 1024 + tid * 4;
    int4 d4 = *(const int4*)(dst + e0);
    atomicAdd(&h[d4.x >> 10], 1);
    atomicAdd(&h[d4.y >> 10], 1);
    atomicAdd(&h[d4.z >> 10], 1);
    atomicAdd(&h[d4.w >> 10], 1);
    __syncthreads();
    if (tid < NRANGE && h[tid]) atomicAdd(&rangeCnt[tid], h[tid]);
}

// ---------------------------------------------------------------------------
// Exclusive scan of 98 range counts -> rangeBase[99] + gcur (P1 cursors).
// ---------------------------------------------------------------------------
__global__ __launch_bounds__(128) void scan98_kernel(
    const int* __restrict__ rangeCnt, int* __restrict__ rangeBase,
    int* __restrict__ gcur, int* __restrict__ rowptr)
{
    __shared__ int sd[128];
    int tid = threadIdx.x;
    int v = (tid < NRANGE) ? rangeCnt[tid] : 0;
    sd[tid] = v;
    __syncthreads();
    for (int o = 1; o < 128; o <<= 1) {
        int t = (tid >= o) ? sd[tid - o] : 0;
        __syncthreads();
        sd[tid] += t;
        __syncthreads();
    }
    if (tid < NRANGE) { int ex = sd[tid] - v; rangeBase[tid] = ex; gcur[tid] = ex; }
    if (tid == 0) { rangeBase[NRANGE] = NE; rowptr[NN] = NE; }
}

// ---------------------------------------------------------------------------
// P1: coarse bin by dst range, block-synchronous LDS staging (grouped runs).
// ---------------------------------------------------------------------------
__global__ __launch_bounds__(256) void p1_bin_kernel(
    const int* __restrict__ src, const int* __restrict__ dst,
    const float* __restrict__ w, int* __restrict__ gcur,
    int2* __restrict__ ecoarse)
{
    __shared__ int2 stage[1024];
    __shared__ unsigned char sbkt[1024];
    __shared__ int cnt[128], ofs[128], gpos[128], sd[128];

    int tid = threadIdx.x;
    int e0 = blockIdx.x * 1024 + tid * 4;
    int4   s4 = *(const int4*)(src + e0);
    int4   d4 = *(const int4*)(dst + e0);
    float4 w4 = *(const float4*)(w + e0);

    if (tid < 128) cnt[tid] = 0;
    __syncthreads();

    int ss[4] = {s4.x, s4.y, s4.z, s4.w};
    int dd[4] = {d4.x, d4.y, d4.z, d4.w};
    float ww[4] = {w4.x, w4.y, w4.z, w4.w};
    int b[4], p[4];
#pragma unroll
    for (int i = 0; i < 4; ++i) {
        b[i] = dd[i] >> 10;
        p[i] = atomicAdd(&cnt[b[i]], 1);
    }
    __syncthreads();

    int cv = (tid < 128) ? cnt[tid] : 0;
    if (tid < 128) sd[tid] = cv;
    __syncthreads();
    for (int o = 1; o < 128; o <<= 1) {
        int t = (tid >= o && tid < 128) ? sd[tid - o] : 0;
        __syncthreads();
        if (tid < 128) sd[tid] += t;
        __syncthreads();
    }
    if (tid < 128) ofs[tid] = sd[tid] - cv;
    if (tid < NRANGE && cv > 0) gpos[tid] = atomicAdd(&gcur[tid], cv);
    __syncthreads();

#pragma unroll
    for (int i = 0; i < 4; ++i) {
        int slot = ofs[b[i]] + p[i];
        stage[slot] = make_int2(ss[i] | ((dd[i] & 1023) << 17), __float_as_int(ww[i]));
        sbkt[slot] = (unsigned char)b[i];
    }
    __syncthreads();

    for (int j = tid; j < 1024; j += 256) {
        int bb = sbkt[j];
        ecoarse[gpos[bb] + (j - ofs[bb])] = stage[j];
    }
}

// ---------------------------------------------------------------------------
// P2: per-range degree count + LDS scan -> rowptr, then place into the
// range's L2-resident ebuf window. Grid NRANGE.
// ---------------------------------------------------------------------------
__global__ __launch_bounds__(256) void p2_place_kernel(
    const int2* __restrict__ ecoarse, const int* __restrict__ rangeBase,
    int* __restrict__ rowptr, int2* __restrict__ ebuf)
{
    __shared__ int cnt[1024];
    __shared__ int ssum[256];
    int r = blockIdx.x, tid = threadIdx.x;
    int beg = rangeBase[r], end = rangeBase[r + 1];

    for (int i = tid; i < 1024; i += 256) cnt[i] = 0;
    __syncthreads();

    for (int j = beg + tid; j < end; j += 256) {
        int2 rec = ecoarse[j];
        atomicAdd(&cnt[(rec.x >> 17) & 1023], 1);
    }
    __syncthreads();

    int base4 = tid * 4;
    int c0 = cnt[base4], c1 = cnt[base4 + 1], c2 = cnt[base4 + 2], c3 = cnt[base4 + 3];
    int s = c0 + c1 + c2 + c3;
    ssum[tid] = s;
    __syncthreads();
    for (int o = 1; o < 256; o <<= 1) {
        int t = (tid >= o) ? ssum[tid - o] : 0;
        __syncthreads();
        ssum[tid] += t;
        __syncthreads();
    }
    int p0 = beg + ssum[tid] - s;
    int p1 = p0 + c0, p2 = p1 + c1, p3 = p2 + c2;

    int node0 = (r << 10) + base4;
    if (node0 < NN)     rowptr[node0]     = p0;
    if (node0 + 1 < NN) rowptr[node0 + 1] = p1;
    if (node0 + 2 < NN) rowptr[node0 + 2] = p2;
    if (node0 + 3 < NN) rowptr[node0 + 3] = p3;
    cnt[base4] = p0; cnt[base4 + 1] = p1; cnt[base4 + 2] = p2; cnt[base4 + 3] = p3;
    __syncthreads();

    for (int j = beg + tid; j < end; j += 256) {
        int2 rec = ecoarse[j];
        int dl = (rec.x >> 17) & 1023;
        int p = atomicAdd(&cnt[dl], 1);
        ebuf[p] = make_int2(rec.x & 0x1FFFF, rec.y);
    }
}

// ---------------------------------------------------------------------------
// Fused GraphConv: persistent blocks (FGRID), each handles GPB contiguous
// groups of 16 nodes. Per group: CSR-gather agg rows (R6 structure: wave per
// 4 nodes, lane=feature, unroll-4 MLP) written DIRECTLY into MFMA A-fragment
// LDS layout; h rows staged coalesced by threads 128-255; one barrier;
// 4 MFMAs (K=128, B-frags of [Wrel;Wroot] in 16 VGPRs, loaded once/block);
// bias(+ReLU) epilogue. Double-buffered LDS: MFMA(g) overlaps gather(g+1).
// ---------------------------------------------------------------------------
template <bool RELU, bool OUT32>
__global__ __launch_bounds__(256) void fused_gconv_kernel(
    const unsigned short* __restrict__ hb,   // node features bf16 (gather + root)
    const int* __restrict__ rowptr,
    const int2* __restrict__ ebuf,
    const float* __restrict__ Wrel,
    const float* __restrict__ brel,
    const float* __restrict__ Wroot,
    void* __restrict__ outp)
{
    __shared__ __align__(16) unsigned short Ast[2][256][8];   // 8 KB

    int tid = threadIdx.x;
    int lane = tid & 63;
    int wv = tid >> 6;
    int quad = lane >> 4;
    int m16 = lane & 15;
    int n = wv * 16 + m16;           // output column

    // ---- B fragments (loaded once per block): 4 ksteps x 8 bf16
    bf16x8 bfrag[4];
#pragma unroll
    for (int t = 0; t < 4; ++t) {
#pragma unroll
        for (int j = 0; j < 8; ++j) {
            int k = t * 32 + quad * 8 + j;
            float wval = (k < 64) ? Wrel[k * 64 + n] : Wroot[(k - 64) * 64 + n];
            bfrag[t][j] = (short)f2bf(wval);
        }
    }
    float bias = brel[n];

    // frag-write coords for gather output (feature d = lane):
    int ft = lane >> 5;              // kstep 0/1
    int fq = (lane >> 3) & 3;        // quad within kstep
    int fj = lane & 7;               // element within 8
    // h staging coords (threads 128..255 -> ksteps 2,3):
    int hs_ms = lane & 15;
    int hs_cOff = (tid >> 6) * 32 + (lane >> 4) * 8 - 64;   // 0..63 when tid>=128

    int g0 = blockIdx.x * GPB;

    // ---- gather one group into buffer buf
    auto do_group = [&](int g, int buf) {
        uint4 hreg;
        if (tid >= 128)
            hreg = *(const uint4*)(hb + ((size_t)g * 16 + hs_ms) * DD + hs_cOff);
#pragma unroll
        for (int s = 0; s < 4; ++s) {
            int node = g * 16 + wv * 4 + s;
            int beg = __builtin_amdgcn_readfirstlane(rowptr[node]);
            int end = __builtin_amdgcn_readfirstlane(rowptr[node + 1]);
            float a0 = 0.f, a1 = 0.f, a2 = 0.f, a3 = 0.f;
            int j = beg;
            for (; j + 4 <= end; j += 4) {
                int2 e0 = ebuf[j], e1 = ebuf[j + 1], e2 = ebuf[j + 2], e3 = ebuf[j + 3];
                unsigned short u0 = hb[(size_t)e0.x * DD + lane];
                unsigned short u1 = hb[(size_t)e1.x * DD + lane];
                unsigned short u2 = hb[(size_t)e2.x * DD + lane];
                unsigned short u3 = hb[(size_t)e3.x * DD + lane];
                a0 = fmaf(__int_as_float(e0.y), __uint_as_float((unsigned)u0 << 16), a0);
                a1 = fmaf(__int_as_float(e1.y), __uint_as_float((unsigned)u1 << 16), a1);
                a2 = fmaf(__int_as_float(e2.y), __uint_as_float((unsigned)u2 << 16), a2);
                a3 = fmaf(__int_as_float(e3.y), __uint_as_float((unsigned)u3 << 16), a3);
            }
            for (; j < end; ++j) {
                int2 e0 = ebuf[j];
                unsigned short u0 = hb[(size_t)e0.x * DD + lane];
                a0 = fmaf(__int_as_float(e0.y), __uint_as_float((unsigned)u0 << 16), a0);
            }
            float v = (a0 + a1) + (a2 + a3);
            Ast[buf][ft * 64 + fq * 16 + (wv * 4 + s)][fj] = f2bf(v);
        }
        if (tid >= 128)
            *(uint4*)&Ast[buf][tid][0] = hreg;
    };

    // prologue: group g0 into buf 0
    do_group(g0, 0);
    __syncthreads();

    int buf = 0;
#pragma unroll 1
    for (int i = 0; i < GPB; ++i) {
        int g = g0 + i;

        // A fragments for g, then MFMA (latency hidden under next gather)
        bf16x8 a[4];
#pragma unroll
        for (int t = 0; t < 4; ++t)
            a[t] = *(const bf16x8*)&Ast[buf][t * 64 + lane][0];
        f32x4 c = {0.f, 0.f, 0.f, 0.f};
#pragma unroll
        for (int t = 0; t < 4; ++t)
            c = __builtin_amdgcn_mfma_f32_16x16x32_bf16(a[t], bfrag[t], c, 0, 0, 0);

        // gather next group into the other buffer
        if (i < GPB - 1) do_group(g + 1, buf ^ 1);

        // epilogue: bias (+ReLU), store
#pragma unroll
        for (int reg = 0; reg < 4; ++reg) {
            int row = quad * 4 + reg;
            size_t node = (size_t)g * 16 + row;
            float v = c[reg] + bias;
            if (RELU) v = fmaxf(v, 0.f);
            if (OUT32) ((float*)outp)[node * DD + n] = v;
            else       ((unsigned short*)outp)[node * DD + n] = f2bf(v);
        }
        __syncthreads();
        buf ^= 1;
    }
}

extern "C" void kernel_launch(void* const* d_in, const int* in_sizes, int n_in,
                              void* d_out, int out_size, void* d_ws, size_t ws_size,
                              hipStream_t stream)
{
    const float* x     = (const float*)d_in[0];
    const int*   ei    = (const int*)d_in[1];
    const float* w     = (const float*)d_in[2];
    const float* Wrel1 = (const float*)d_in[4];
    const float* brel1 = (const float*)d_in[5];
    const float* Wroot1= (const float*)d_in[6];
    const float* Wrel2 = (const float*)d_in[7];
    const float* brel2 = (const float*)d_in[8];
    const float* Wroot2= (const float*)d_in[9];
    const float* Wrel3 = (const float*)d_in[10];
    const float* brel3 = (const float*)d_in[11];
    const float* Wroot3= (const float*)d_in[12];

    float* out = (float*)d_out;

    // workspace: ebuf | region2 (ecoarse -> xb after build) | h1b | h2b | ints
    char* ws = (char*)d_ws;
    int2*  ebuf    = (int2*)ws;                       ws += (size_t)NE * 8;          // 10.24 MB
    int2*  ecoarse = (int2*)ws;
    unsigned short* xb  = (unsigned short*)ws;        ws += (size_t)NN * DD * 2;     // 12.8 MB (>= ecoarse)
    unsigned short* h1b = (unsigned short*)ws;        ws += (size_t)NN * DD * 2;     // 12.8 MB
    unsigned short* h2b = (unsigned short*)ws;        ws += (size_t)NN * DD * 2;     // 12.8 MB
    int*   rowptr  = (int*)ws;                        ws += (size_t)(NN + 1) * 4;
    int*   rangeCnt = (int*)ws;                       ws += (size_t)128 * 4;
    int*   rangeBase = (int*)ws;                      ws += (size_t)128 * 4;
    int*   gcur    = (int*)ws;

    const int* src = ei;
    const int* dst = ei + NE;

    // ---- CSR build (ecoarse region reused as xb afterwards) ----
    hipMemsetAsync(rangeCnt, 0, NRANGE * 4, stream);
    hist2_kernel<<<1250, 256, 0, stream>>>(dst, rangeCnt);
    scan98_kernel<<<1, 128, 0, stream>>>(rangeCnt, rangeBase, gcur, rowptr);
    p1_bin_kernel<<<1250, 256, 0, stream>>>(src, dst, w, gcur, ecoarse);
    p2_place_kernel<<<NRANGE, 256, 0, stream>>>(ecoarse, rangeBase, rowptr, ebuf);

    // ---- xb = bf16(x) (ecoarse dead now) ----
    f32_to_bf16_kernel<<<6250, 256, 0, stream>>>(x, xb);

    // ---- Layer 1: fused gconv(xb) -> h1b (bf16, ReLU) ----
    fused_gconv_kernel<true, false><<<FGRID, 256, 0, stream>>>(
        xb, rowptr, ebuf, Wrel1, brel1, Wroot1, h1b);

    // ---- Layer 2: fused gconv(h1b) -> h2b (bf16, ReLU) ----
    fused_gconv_kernel<true, false><<<FGRID, 256, 0, stream>>>(
        h1b, rowptr, ebuf, Wrel2, brel2, Wroot2, h2b);

    // ---- Layer 3: fused gconv(h2b) -> out (fp32) ----
    fused_gconv_kernel<false, true><<<FGRID, 256, 0, stream>>>(
        h2b, rowptr, ebuf, Wrel3, brel3, Wroot3, out);
}